// Round 2
// baseline (55245.953 us; speedup 1.0000x reference)
//
#include <hip/hip_runtime.h>
#include <hip/hip_bf16.h>

#define B_  32
#define T_  64
#define S_  64
#define E_  256
#define H_  512
#define A_  512
#define DV_ 32000
#define H4_ 2048
#define NBLK 512
#define GRP_N 64

typedef __attribute__((ext_vector_type(8))) short short8;
typedef __attribute__((ext_vector_type(4))) float floatx4;

__device__ __forceinline__ float sig_(float x) {
    return __fdividef(1.f, 1.f + __expf(-x));
}
__device__ __forceinline__ float tanh_(float x) {
    float e = __expf(2.f * x);
    return __fdividef(e - 1.f, e + 1.f);
}
__device__ __forceinline__ unsigned short f2bf(float f) {
    union { float f; unsigned u; } v; v.f = f;
    unsigned r = (v.u + 0x7fffu + ((v.u >> 16) & 1u)) >> 16;
    return (unsigned short)r;
}
__device__ __forceinline__ void fma8(float& a, const float4& h0, const float4& h1v,
                                     const float4& w0, const float4& w1) {
    a = fmaf(h0.x, w0.x, a); a = fmaf(h0.y, w0.y, a);
    a = fmaf(h0.z, w0.z, a); a = fmaf(h0.w, w0.w, a);
    a = fmaf(h1v.x, w1.x, a); a = fmaf(h1v.y, w1.y, a);
    a = fmaf(h1v.z, w1.z, a); a = fmaf(h1v.w, w1.w, a);
}

// Two-level grid barrier: 8 groups (blockIdx&7) of 64, monotonic generations.
__device__ __forceinline__ void gbar(int* bar, int gen) {
    __threadfence();
    __syncthreads();
    if (threadIdx.x == 0) {
        int g = blockIdx.x & 7;
        int* grp  = bar + g * 16;
        int* flag = bar + 128 + g * 16;
        int* root = bar + 256;
        int a = __hip_atomic_fetch_add(grp, 1, __ATOMIC_ACQ_REL, __HIP_MEMORY_SCOPE_AGENT);
        if (a == gen * GRP_N - 1) {
            int r = __hip_atomic_fetch_add(root, 1, __ATOMIC_ACQ_REL, __HIP_MEMORY_SCOPE_AGENT);
            if (r == gen * 8 - 1) {
#pragma unroll
                for (int i = 0; i < 8; ++i)
                    __hip_atomic_store(bar + 128 + i * 16, gen, __ATOMIC_RELEASE,
                                       __HIP_MEMORY_SCOPE_AGENT);
            }
        }
        while (__hip_atomic_load(flag, __ATOMIC_ACQUIRE, __HIP_MEMORY_SCOPE_AGENT) < gen)
            __builtin_amdgcn_s_sleep(2);
    }
    __syncthreads();
}

// ---------------------------------------------------------------------------
// Setup: blocks 0..255: encp = enc @ W2 + b2 (8 rows each, W2 L2-resident)
//        block 256: h0g/h1g init; block 257: zero ctxbuf[0], lbuf, barrier
// ---------------------------------------------------------------------------
__global__ __launch_bounds__(256) void k_setup(
    const float* __restrict__ enc, const float* __restrict__ W2,
    const float* __restrict__ b2, const float* __restrict__ hidden0,
    float* __restrict__ encp, float* __restrict__ h0g, float* __restrict__ h1g,
    float* __restrict__ ctxbuf, float* __restrict__ lbuf, int* __restrict__ bar)
{
    int bid = blockIdx.x, tid = threadIdx.x;
    if (bid < 256) {
        __shared__ __align__(16) float ence[8 * 512];
        int r0 = bid * 8;
        const float4* esrc = (const float4*)(enc + (size_t)r0 * 512);
        float4* edst = (float4*)ence;
        for (int i = tid; i < 1024; i += 256) edst[i] = esrc[i];
        __syncthreads();
        float a0[8], a1[8];
#pragma unroll
        for (int r = 0; r < 8; ++r) { a0[r] = 0.f; a1[r] = 0.f; }
        for (int k = 0; k < 512; k += 4) {
            float4 e4[8];
#pragma unroll
            for (int r = 0; r < 8; ++r) e4[r] = *(const float4*)&ence[r * 512 + k];
#pragma unroll
            for (int kk = 0; kk < 4; ++kk) {
                float w0 = W2[(size_t)(k + kk) * 512 + tid];
                float w1 = W2[(size_t)(k + kk) * 512 + 256 + tid];
#pragma unroll
                for (int r = 0; r < 8; ++r) {
                    float ev = (kk == 0) ? e4[r].x : (kk == 1) ? e4[r].y
                             : (kk == 2) ? e4[r].z : e4[r].w;
                    a0[r] = fmaf(ev, w0, a0[r]);
                    a1[r] = fmaf(ev, w1, a1[r]);
                }
            }
        }
        float bb0 = b2[tid], bb1 = b2[256 + tid];
#pragma unroll
        for (int r = 0; r < 8; ++r) {
            encp[(size_t)(r0 + r) * 512 + tid] = a0[r] + bb0;
            encp[(size_t)(r0 + r) * 512 + 256 + tid] = a1[r] + bb1;
        }
    } else if (bid == 256) {
        for (int i = tid; i < 16384; i += 256) {
            h0g[i] = hidden0[i];
            h1g[i] = hidden0[16384 + i];
        }
    } else {
        for (int i = tid; i < 16384; i += 256) ctxbuf[i] = 0.f;
        if (tid < 32) lbuf[tid] = 0.f;
        for (int i = tid; i < 512; i += 256) bar[i] = 0;
    }
}

// ---------------------------------------------------------------------------
// Wd [512,32000] fp32 -> WdT [32000,512] bf16
// ---------------------------------------------------------------------------
__global__ __launch_bounds__(256) void k_wdt(const float* __restrict__ Wd,
                                             unsigned short* __restrict__ WdT)
{
    __shared__ float tle[64 * 65];
    int kb = blockIdx.x & 7, nb = blockIdx.x >> 3;
    int k0 = kb * 64, n0 = nb * 64;
    int tid = threadIdx.x;
    for (int i = 0; i < 16; ++i) {
        int e = tid + 256 * i;
        int kk = e >> 6, nn = e & 63;
        tle[kk * 65 + nn] = Wd[(size_t)(k0 + kk) * DV_ + n0 + nn];
    }
    __syncthreads();
    for (int i = 0; i < 16; ++i) {
        int e = tid + 256 * i;
        int nn = e >> 6, kk = e & 63;
        WdT[(size_t)(n0 + nn) * H_ + k0 + kk] = f2bf(tle[kk * 65 + nn]);
    }
}

// ---------------------------------------------------------------------------
// Cooperative recurrence: weights LDS-resident, 4 phases/step, custom barrier
// ---------------------------------------------------------------------------
struct DecodeParams {
    const float *x, *enc, *encp;
    const float *W1, *b1, *Wh0, *Wh1, *Wx0, *Wx1, *bL0, *bL1, *V, *bV, *cell0;
    float *qg, *p0g, *p1g, *ctxbuf, *lbuf, *h0g, *h1g;
    unsigned short *h1b;
    float *out_hc;
    int *bar;
};

__global__ __launch_bounds__(128, 2) void k_decode(DecodeParams p)
{
    const int bid = blockIdx.x, tid = threadIdx.x;
    const int bg = tid >> 4, kq = tid & 15;   // bg: 4 batches each; kq: 32-k slice

    __shared__ __align__(16) float wp[9 * 576];     // P1 col slices (padded)
    __shared__ __align__(16) float wx0c[4 * 576];   // Wx0 ctx rows, gate cols of j=bid
    __shared__ __align__(16) float wx0x[4 * 320];   // Wx0 x rows (K=256)
    __shared__ __align__(16) float wx1s[4 * 576];   // Wx1 gate cols
    __shared__ __align__(16) float qs[512];
    __shared__ float es[16];

    // ---- stage weights once (strided one-time loads, L2-amortized) ----
    const int U0 = bid * 9;
    for (int c = 0; c < 9; ++c) {
        int u = U0 + c;
        const float* W; int col, ldW;
        if (u < 512)       { W = p.W1;  col = u;        ldW = 512; }
        else if (u < 2560) { W = p.Wh0; col = u - 512;  ldW = 2048; }
        else               { W = p.Wh1; col = u - 2560; ldW = 2048; }
        for (int k = tid; k < 512; k += 128)
            wp[c * 576 + (k >> 5) * 36 + (k & 31)] = W[(size_t)k * ldW + col];
    }
    for (int g = 0; g < 4; ++g) {
        int n = bid + 512 * g;
        for (int k = tid; k < 512; k += 128) {
            wx0c[g * 576 + (k >> 5) * 36 + (k & 31)] = p.Wx0[(size_t)k * H4_ + n];
            wx1s[g * 576 + (k >> 5) * 36 + (k & 31)] = p.Wx1[(size_t)k * H4_ + n];
        }
        for (int k = tid; k < 256; k += 128)
            wx0x[g * 320 + (k >> 4) * 20 + (k & 15)] = p.Wx0[(size_t)(512 + k) * H4_ + n];
    }
    float c0r[4], c1r[4];
#pragma unroll
    for (int i = 0; i < 4; ++i) {
        int b = bg * 4 + i;
        c0r[i] = p.cell0[b * 512 + bid];
        c1r[i] = p.cell0[16384 + b * 512 + bid];
    }
    const int atype = min(max(512 - U0, 0), 9);    // cols < atype: q (h1)
    const int btype = min(max(2560 - U0, 0), 9);   // [atype,btype): p0 (h0); rest: p1 (h1)
    float* colbase[9]; int colld[9]; float colbias[9];
    for (int c = 0; c < 9; ++c) {
        int u = U0 + c;
        if (u < 512)       { colbase[c] = p.qg  + u;          colld[c] = 512;  colbias[c] = p.b1[u]; }
        else if (u < 2560) { colbase[c] = p.p0g + (u - 512);  colld[c] = 2048; colbias[c] = 0.f; }
        else               { colbase[c] = p.p1g + (u - 2560); colld[c] = 2048; colbias[c] = 0.f; }
    }
    const bool needH1 = (atype > 0) || (btype < 9);
    const bool needH0 = (btype > atype);
    float bL0r[4], bL1r[4];
#pragma unroll
    for (int g = 0; g < 4; ++g) {
        bL0r[g] = p.bL0[bid + 512 * g];
        bL1r[g] = p.bL1[bid + 512 * g];
    }
    const float bV0 = p.bV[0];
    __syncthreads();

    int gen = 1;
    for (int t = 0; t < T_; ++t) {
        // ================= P1: q = h1@W1+b1, p0 = h0@Wh0, p1 = h1@Wh1 =====
        {
            float acc[9][4];
#pragma unroll
            for (int c = 0; c < 9; ++c)
#pragma unroll
                for (int i = 0; i < 4; ++i) acc[c][i] = 0.f;
#pragma unroll
            for (int kc = 0; kc < 4; ++kc) {
                int kb = kq * 32 + kc * 8;
                float4 h1a[4][2], h0a[4][2];
                if (needH1) {
#pragma unroll
                    for (int i = 0; i < 4; ++i) {
                        const float* s = p.h1g + (bg * 4 + i) * 512 + kb;
                        h1a[i][0] = *(const float4*)s;
                        h1a[i][1] = *(const float4*)(s + 4);
                    }
                }
                if (needH0) {
#pragma unroll
                    for (int i = 0; i < 4; ++i) {
                        const float* s = p.h0g + (bg * 4 + i) * 512 + kb;
                        h0a[i][0] = *(const float4*)s;
                        h0a[i][1] = *(const float4*)(s + 4);
                    }
                }
                int wofs = kq * 36 + kc * 8;
#pragma unroll
                for (int c = 0; c < 9; ++c) {
                    float4 w0 = *(const float4*)&wp[c * 576 + wofs];
                    float4 w1 = *(const float4*)&wp[c * 576 + wofs + 4];
                    if (c >= atype && c < btype) {
#pragma unroll
                        for (int i = 0; i < 4; ++i) fma8(acc[c][i], h0a[i][0], h0a[i][1], w0, w1);
                    } else {
#pragma unroll
                        for (int i = 0; i < 4; ++i) fma8(acc[c][i], h1a[i][0], h1a[i][1], w0, w1);
                    }
                }
            }
#pragma unroll
            for (int c = 0; c < 9; ++c)
#pragma unroll
                for (int i = 0; i < 4; ++i) {
                    float v = acc[c][i];
                    v += __shfl_xor(v, 8); v += __shfl_xor(v, 4);
                    v += __shfl_xor(v, 2); v += __shfl_xor(v, 1);
                    acc[c][i] = v;
                }
            if (kq == 0) {
#pragma unroll
                for (int c = 0; c < 9; ++c)
#pragma unroll
                    for (int i = 0; i < 4; ++i)
                        colbase[c][(bg * 4 + i) * colld[c]] = acc[c][i] + colbias[c];
            }
        }
        gbar(p.bar, gen++);

        // ================= P2: attention (blocks 0..127, 4 per batch) =====
        if (bid < 128) {
            const int b = bid >> 2, sg = bid & 3, s0v = sg * 16;
            for (int i = tid; i < 512; i += 128) qs[i] = p.qg[b * 512 + i];
            // zero next-step accumulation buffers (consumed 2 barriers ago)
            float* ctxn = p.ctxbuf + ((t + 1) & 1) * 16384 + b * 512 + sg * 128;
            ctxn[tid] = 0.f;
            if (sg == 0 && tid == 0) p.lbuf[((t + 1) & 1) * 32 + b] = 0.f;
            __syncthreads();
            const int sl = tid >> 3, ag = tid & 7;
            const float* ep = p.encp + ((size_t)(b * 64 + s0v + sl)) * 512 + ag * 64;
            const float* qq = qs + ag * 64;
            const float* Vv = p.V + ag * 64;
            float sc = 0.f;
            for (int a = 0; a < 64; a += 4) {
                float4 e4 = *(const float4*)(ep + a);
                float4 q4 = *(const float4*)(qq + a);
                float4 v4 = *(const float4*)(Vv + a);
                sc = fmaf(tanh_(e4.x + q4.x), v4.x, sc);
                sc = fmaf(tanh_(e4.y + q4.y), v4.y, sc);
                sc = fmaf(tanh_(e4.z + q4.z), v4.z, sc);
                sc = fmaf(tanh_(e4.w + q4.w), v4.w, sc);
            }
            sc += __shfl_xor(sc, 1); sc += __shfl_xor(sc, 2); sc += __shfl_xor(sc, 4);
            if (ag == 0) es[sl] = __expf(sc + bV0);   // fixed-shift softmax: |score|<=||V||_1~16, fp32-safe
            __syncthreads();
            if (tid == 0) {
                float lp = 0.f;
#pragma unroll
                for (int i = 0; i < 16; ++i) lp += es[i];
                atomicAdd(&p.lbuf[(t & 1) * 32 + b], lp);
            }
            float a0 = 0.f, a1 = 0.f, a2 = 0.f, a3 = 0.f;
            const float* encb = p.enc + ((size_t)(b * 64 + s0v)) * 512 + tid * 4;
            for (int s = 0; s < 16; ++s) {
                float ev = es[s];
                float4 e4 = *(const float4*)(encb + s * 512);
                a0 = fmaf(ev, e4.x, a0); a1 = fmaf(ev, e4.y, a1);
                a2 = fmaf(ev, e4.z, a2); a3 = fmaf(ev, e4.w, a3);
            }
            float* cc = p.ctxbuf + (t & 1) * 16384 + b * 512 + tid * 4;
            atomicAdd(cc + 0, a0); atomicAdd(cc + 1, a1);
            atomicAdd(cc + 2, a2); atomicAdd(cc + 3, a3);
        }
        gbar(p.bar, gen++);

        // ================= P3: z0 = ctx@Wx0c*rl + x@Wx0x + p0 + bL0 =======
        {
            float ac[4][4], ax[4][4];
#pragma unroll
            for (int g = 0; g < 4; ++g)
#pragma unroll
                for (int i = 0; i < 4; ++i) { ac[g][i] = 0.f; ax[g][i] = 0.f; }
            const float* ctxc = p.ctxbuf + (t & 1) * 16384;
#pragma unroll
            for (int kc = 0; kc < 4; ++kc) {
                int kb = kq * 32 + kc * 8;
                float4 ca[4][2];
#pragma unroll
                for (int i = 0; i < 4; ++i) {
                    const float* s = ctxc + (bg * 4 + i) * 512 + kb;
                    ca[i][0] = *(const float4*)s; ca[i][1] = *(const float4*)(s + 4);
                }
                int wofs = kq * 36 + kc * 8;
#pragma unroll
                for (int g = 0; g < 4; ++g) {
                    float4 w0 = *(const float4*)&wx0c[g * 576 + wofs];
                    float4 w1 = *(const float4*)&wx0c[g * 576 + wofs + 4];
#pragma unroll
                    for (int i = 0; i < 4; ++i) fma8(ac[g][i], ca[i][0], ca[i][1], w0, w1);
                }
            }
#pragma unroll
            for (int kc = 0; kc < 2; ++kc) {
                int kb = kq * 16 + kc * 8;
                float4 xa[4][2];
#pragma unroll
                for (int i = 0; i < 4; ++i) {
                    const float* s = p.x + ((size_t)((bg * 4 + i) * 64 + t)) * 256 + kb;
                    xa[i][0] = *(const float4*)s; xa[i][1] = *(const float4*)(s + 4);
                }
                int wofs = kq * 20 + kc * 8;
#pragma unroll
                for (int g = 0; g < 4; ++g) {
                    float4 w0 = *(const float4*)&wx0x[g * 320 + wofs];
                    float4 w1 = *(const float4*)&wx0x[g * 320 + wofs + 4];
#pragma unroll
                    for (int i = 0; i < 4; ++i) fma8(ax[g][i], xa[i][0], xa[i][1], w0, w1);
                }
            }
#pragma unroll
            for (int g = 0; g < 4; ++g)
#pragma unroll
                for (int i = 0; i < 4; ++i) {
                    float v = ac[g][i];
                    v += __shfl_xor(v, 8); v += __shfl_xor(v, 4);
                    v += __shfl_xor(v, 2); v += __shfl_xor(v, 1);
                    ac[g][i] = v;
                    float u = ax[g][i];
                    u += __shfl_xor(u, 8); u += __shfl_xor(u, 4);
                    u += __shfl_xor(u, 2); u += __shfl_xor(u, 1);
                    ax[g][i] = u;
                }
            if (kq == 0) {
#pragma unroll
                for (int i = 0; i < 4; ++i) {
                    int b = bg * 4 + i;
                    float rl = __fdividef(1.f, p.lbuf[(t & 1) * 32 + b]);
                    float z0v = fmaf(ac[0][i], rl, ax[0][i]) + p.p0g[b * 2048 + bid]        + bL0r[0];
                    float z1v = fmaf(ac[1][i], rl, ax[1][i]) + p.p0g[b * 2048 + bid + 512]  + bL0r[1];
                    float z2v = fmaf(ac[2][i], rl, ax[2][i]) + p.p0g[b * 2048 + bid + 1024] + bL0r[2];
                    float z3v = fmaf(ac[3][i], rl, ax[3][i]) + p.p0g[b * 2048 + bid + 1536] + bL0r[3];
                    float ii = sig_(z0v), ff = sig_(z1v), gg = tanh_(z2v), oo = sig_(z3v);
                    float cn = fmaf(ff, c0r[i], ii * gg);
                    float hn = oo * tanh_(cn);
                    c0r[i] = cn;
                    p.h0g[b * 512 + bid] = hn;
                    if (t == 63) {
                        p.out_hc[b * 512 + bid] = hn;
                        p.out_hc[32768 + b * 512 + bid] = cn;
                    }
                }
            }
        }
        gbar(p.bar, gen++);

        // ================= P4: z1 = h0new@Wx1 + p1 + bL1 ==================
        {
            float ac[4][4];
#pragma unroll
            for (int g = 0; g < 4; ++g)
#pragma unroll
                for (int i = 0; i < 4; ++i) ac[g][i] = 0.f;
#pragma unroll
            for (int kc = 0; kc < 4; ++kc) {
                int kb = kq * 32 + kc * 8;
                float4 ha[4][2];
#pragma unroll
                for (int i = 0; i < 4; ++i) {
                    const float* s = p.h0g + (bg * 4 + i) * 512 + kb;
                    ha[i][0] = *(const float4*)s; ha[i][1] = *(const float4*)(s + 4);
                }
                int wofs = kq * 36 + kc * 8;
#pragma unroll
                for (int g = 0; g < 4; ++g) {
                    float4 w0 = *(const float4*)&wx1s[g * 576 + wofs];
                    float4 w1 = *(const float4*)&wx1s[g * 576 + wofs + 4];
#pragma unroll
                    for (int i = 0; i < 4; ++i) fma8(ac[g][i], ha[i][0], ha[i][1], w0, w1);
                }
            }
#pragma unroll
            for (int g = 0; g < 4; ++g)
#pragma unroll
                for (int i = 0; i < 4; ++i) {
                    float v = ac[g][i];
                    v += __shfl_xor(v, 8); v += __shfl_xor(v, 4);
                    v += __shfl_xor(v, 2); v += __shfl_xor(v, 1);
                    ac[g][i] = v;
                }
            if (kq == 0) {
#pragma unroll
                for (int i = 0; i < 4; ++i) {
                    int b = bg * 4 + i;
                    float z0v = ac[0][i] + p.p1g[b * 2048 + bid]        + bL1r[0];
                    float z1v = ac[1][i] + p.p1g[b * 2048 + bid + 512]  + bL1r[1];
                    float z2v = ac[2][i] + p.p1g[b * 2048 + bid + 1024] + bL1r[2];
                    float z3v = ac[3][i] + p.p1g[b * 2048 + bid + 1536] + bL1r[3];
                    float ii = sig_(z0v), ff = sig_(z1v), gg = tanh_(z2v), oo = sig_(z3v);
                    float cn = fmaf(ff, c1r[i], ii * gg);
                    float hn = oo * tanh_(cn);
                    c1r[i] = cn;
                    p.h1g[b * 512 + bid] = hn;
                    p.h1b[((size_t)t * 32 + b) * 512 + bid] = f2bf(hn);
                    if (t == 63) {
                        p.out_hc[16384 + b * 512 + bid] = hn;
                        p.out_hc[49152 + b * 512 + bid] = cn;
                    }
                }
            }
        }
        gbar(p.bar, gen++);
    }
}

// ---------------------------------------------------------------------------
// Logits: [2048,512]bf16 @ [32000,512]bf16^T via MFMA (unchanged, verified)
// ---------------------------------------------------------------------------
__global__ __launch_bounds__(256) void k_logits(
    const unsigned short* __restrict__ Am,
    const unsigned short* __restrict__ Bm,
    const float* __restrict__ bd,
    float* __restrict__ out)
{
    __shared__ __align__(16) unsigned short As[128 * 72];
    __shared__ __align__(16) unsigned short Bs[128 * 72];
    int tid = threadIdx.x;
    int lane = tid & 63, wv = tid >> 6;
    int mt = blockIdx.x & 15, nt = blockIdx.x >> 4;
    int m0 = mt * 128, n0 = nt * 128;
    int wm = wv >> 1, wn = wv & 1;

    floatx4 acc[4][4];
    for (int i = 0; i < 4; ++i)
        for (int j = 0; j < 4; ++j)
            acc[i][j] = (floatx4){0.f, 0.f, 0.f, 0.f};

    for (int kt = 0; kt < 8; ++kt) {
        int k0 = kt * 64;
        __syncthreads();
        for (int i = 0; i < 4; ++i) {
            int chunk = tid + 256 * i;
            int row = chunk >> 3, c8 = chunk & 7;
            uint4 va = *(const uint4*)(Am + (size_t)(m0 + row) * H_ + k0 + c8 * 8);
            *(uint4*)(As + row * 72 + c8 * 8) = va;
            uint4 vb = *(const uint4*)(Bm + (size_t)(n0 + row) * H_ + k0 + c8 * 8);
            *(uint4*)(Bs + row * 72 + c8 * 8) = vb;
        }
        __syncthreads();
        int q8 = (lane >> 4) * 8;
        int rl = lane & 15;
        for (int kk = 0; kk < 64; kk += 32) {
            short8 af[4], bf[4];
            for (int mi = 0; mi < 4; ++mi)
                af[mi] = *(const short8*)(As + (wm * 64 + mi * 16 + rl) * 72 + kk + q8);
            for (int ni = 0; ni < 4; ++ni)
                bf[ni] = *(const short8*)(Bs + (wn * 64 + ni * 16 + rl) * 72 + kk + q8);
            for (int mi = 0; mi < 4; ++mi)
                for (int ni = 0; ni < 4; ++ni)
                    acc[mi][ni] = __builtin_amdgcn_mfma_f32_16x16x32_bf16(
                        af[mi], bf[ni], acc[mi][ni], 0, 0, 0);
        }
    }

    int rl = lane & 15, qd = lane >> 4;
    for (int ni = 0; ni < 4; ++ni) {
        int n = n0 + wn * 64 + ni * 16 + rl;
        float bias = bd[n];
        for (int mi = 0; mi < 4; ++mi) {
            for (int r = 0; r < 4; ++r) {
                int m = m0 + wm * 64 + mi * 16 + qd * 4 + r;
                int tt = m >> 5, bb = m & 31;
                out[((size_t)(bb * T_ + tt)) * DV_ + n] = acc[mi][ni][r] + bias;
            }
        }
    }
}

// ---------------------------------------------------------------------------
extern "C" void kernel_launch(void* const* d_in, const int* in_sizes, int n_in,
                              void* d_out, int out_size, void* d_ws, size_t ws_size,
                              hipStream_t stream)
{
    const float* x       = (const float*)d_in[0];
    const float* hidden0 = (const float*)d_in[1];
    const float* cell0   = (const float*)d_in[2];
    const float* enc     = (const float*)d_in[3];
    const float* W1      = (const float*)d_in[4];
    const float* b1      = (const float*)d_in[5];
    const float* W2      = (const float*)d_in[6];
    const float* b2      = (const float*)d_in[7];
    const float* V       = (const float*)d_in[8];
    const float* bV      = (const float*)d_in[9];
    const float* Wx0     = (const float*)d_in[10];
    const float* Wh0     = (const float*)d_in[11];
    const float* bL0     = (const float*)d_in[12];
    const float* Wx1     = (const float*)d_in[13];
    const float* Wh1     = (const float*)d_in[14];
    const float* bL1     = (const float*)d_in[15];
    const float* Wd      = (const float*)d_in[16];
    const float* bd      = (const float*)d_in[17];

    char* ws = (char*)d_ws;
    size_t off = 0;
    auto alloc = [&](size_t bytes) -> void* {
        void* ptr = ws + off;
        off = (off + bytes + 255) & ~(size_t)255;
        return ptr;
    };
    unsigned short* WdT = (unsigned short*)alloc((size_t)DV_ * H_ * 2);
    float* encp   = (float*)alloc((size_t)B_ * S_ * A_ * 4);
    float* qg     = (float*)alloc((size_t)B_ * A_ * 4);
    float* p0g    = (float*)alloc((size_t)B_ * H4_ * 4);
    float* p1g    = (float*)alloc((size_t)B_ * H4_ * 4);
    float* ctxbuf = (float*)alloc((size_t)2 * B_ * H_ * 4);
    float* lbuf   = (float*)alloc((size_t)64 * 4);
    float* h0g    = (float*)alloc((size_t)B_ * H_ * 4);
    float* h1g    = (float*)alloc((size_t)B_ * H_ * 4);
    unsigned short* h1b = (unsigned short*)alloc((size_t)T_ * B_ * H_ * 2);
    int* bar      = (int*)alloc(4096);

    float* out = (float*)d_out;
    float* out_hc = out + (size_t)B_ * T_ * DV_;

    hipLaunchKernelGGL(k_setup, dim3(258), dim3(256), 0, stream,
                       enc, W2, b2, hidden0, encp, h0g, h1g, ctxbuf, lbuf, bar);
    hipLaunchKernelGGL(k_wdt, dim3(4000), dim3(256), 0, stream, Wd, WdT);

    DecodeParams p;
    p.x = x; p.enc = enc; p.encp = encp;
    p.W1 = W1; p.b1 = b1; p.Wh0 = Wh0; p.Wh1 = Wh1;
    p.Wx0 = Wx0; p.Wx1 = Wx1; p.bL0 = bL0; p.bL1 = bL1;
    p.V = V; p.bV = bV; p.cell0 = cell0;
    p.qg = qg; p.p0g = p0g; p.p1g = p1g;
    p.ctxbuf = ctxbuf; p.lbuf = lbuf;
    p.h0g = h0g; p.h1g = h1g; p.h1b = h1b;
    p.out_hc = out_hc; p.bar = bar;
    void* args[] = { &p };
    hipLaunchCooperativeKernel((void*)k_decode, dim3(NBLK), dim3(128), args, 0, stream);

    hipLaunchKernelGGL(k_logits, dim3(4000), dim3(256), 0, stream, h1b, WdT, bd, out);
}